// Round 8
// baseline (2197.552 us; speedup 1.0000x reference)
//
#include <hip/hip_runtime.h>
#include <hip/hip_bf16.h>

#define N_NODES 100000
#define N_EDGES 3200000
#define NBKT 782     // ceil(N_NODES/128): bucket = dst>>7
#define BKT_CAP 5376 // avg 4092 edges/bucket, +20 sigma margin

typedef __hip_bfloat16 bf16;
typedef unsigned int uint;
typedef __attribute__((ext_vector_type(8))) short bf16x8;
typedef __attribute__((ext_vector_type(4))) float f32x4;

__device__ __forceinline__ float b2f(bf16 v) { return __bfloat162float(v); }

__device__ __forceinline__ float bits2f(unsigned short w) {
    union { unsigned short u; bf16 b; } c;
    c.u = w;
    return __bfloat162float(c.b);
}
__device__ __forceinline__ unsigned short f2bits(float f) {  // truncate
    return (unsigned short)(__float_as_uint(f) >> 16);
}
__device__ __forceinline__ unsigned short f2bf_bits(float f) {  // RNE
    bf16 b = __float2bfloat16(f);
    unsigned short u;
    __builtin_memcpy(&u, &b, 2);
    return u;
}

// runtime dtype accessors -------------------------------------------------
__device__ __forceinline__ int get_idx(const void* ei, long long pos, int is64) {
    if (is64) return (int)((const long long*)ei)[pos];
    return ((const int*)ei)[pos];
}
__device__ __forceinline__ float get_f(const void* p, long long pos, int isbf) {
    if (isbf) return b2f(((const bf16*)p)[pos]);
    return ((const float*)p)[pos];
}

// ---------------- dtype detection (1 wave) ----------------
__global__ void detect_kernel(const void* __restrict__ x,
                              const void* __restrict__ ei,
                              int* __restrict__ flags) {
    int lane = threadIdx.x;  // 64 threads
    const unsigned short* xw = (const unsigned short*)x;
    float v = bits2f(xw[2 * lane]);
    bool plaus = (v == v) && fabsf(v) > 1e-3f && fabsf(v) < 1e2f;
    unsigned long long m1 = __ballot(plaus);
    const int* iw = (const int*)ei;
    bool z = (iw[2 * lane + 1] == 0);
    unsigned long long m2 = __ballot(z);
    if (lane == 0) {
        flags[0] = (__popcll(m1) >= 32) ? 1 : 0;
        flags[1] = (__popcll(m2) == 64) ? 1 : 0;
    }
}

// ---------------- pass A: bucket edges by dst>>7 ----------------
// 782 blocks x 4096 edges. Packed entry: (dst&127)<<17 | src  (24 bits)
__global__ __launch_bounds__(256) void scatterA_kernel(
    const void* __restrict__ ei, int* __restrict__ bucket_cursor,
    uint* __restrict__ bucket_data, const int* __restrict__ flags) {
    __shared__ int lhist[NBKT];
    __shared__ int lbase[NBKT];
    int is64 = flags[1];
    int t = threadIdx.x;
    int chunk0 = blockIdx.x * 4096;

    for (int i = t; i < NBKT; i += 256) lhist[i] = 0;
    __syncthreads();
    for (int j = 0; j < 16; j++) {
        int e = chunk0 + j * 256 + t;
        if (e < N_EDGES) {
            int d = get_idx(ei, (long long)N_EDGES + e, is64);
            atomicAdd(&lhist[d >> 7], 1);
        }
    }
    __syncthreads();
    for (int i = t; i < NBKT; i += 256) {
        int c = lhist[i];
        lbase[i] = c ? atomicAdd(&bucket_cursor[i], c) : 0;
        lhist[i] = 0;  // reuse as local cursor
    }
    __syncthreads();
    for (int j = 0; j < 16; j++) {
        int e = chunk0 + j * 256 + t;
        if (e < N_EDGES) {
            int s = get_idx(ei, e, is64);
            int d = get_idx(ei, (long long)N_EDGES + e, is64);
            int b = d >> 7;
            int o = lbase[b] + atomicAdd(&lhist[b], 1);
            if (o < BKT_CAP)
                bucket_data[(long long)b * BKT_CAP + o] = ((uint)(d & 127) << 17) | (uint)s;
        }
    }
}

// ---------------- layer-1 aggregation: per-bucket LDS scatter-accumulate ----------------
// block (1024 thr) owns 128 dst nodes; streams unordered entries, reads x[src]
// rows vectorized, ds_add_f32 into padded LDS accumulator; writes mean + deg.
__global__ __launch_bounds__(1024) void aggX_kernel(
    const void* __restrict__ x, const int* __restrict__ bucket_cnt,
    const uint* __restrict__ bucket_data, bf16* __restrict__ aggbuf,
    int* __restrict__ deg_out, const int* __restrict__ flags) {
    __shared__ float acc[128][65];  // stride 65: bank=(ld+8s+j)%32, ~2-way
    __shared__ int lh[128];
    int b = blockIdx.x;
    int t = threadIdx.x;
    int isbf = flags[0];
    int cnt = min(bucket_cnt[b], BKT_CAP);
    const uint* bd = bucket_data + (long long)b * BKT_CAP;

    float* accf = &acc[0][0];
    for (int i = t; i < 128 * 65; i += 1024) accf[i] = 0.0f;
    if (t < 128) lh[t] = 0;
    __syncthreads();

    int wv = t >> 6, lane = t & 63;
    if (isbf) {
        // 8 edges per wave-iter; lane = edge(3b) x chunk(3b); row = 8 uint4
        int e8 = lane >> 3, q8 = lane & 7;
        const uint4* xr4 = (const uint4*)x;
        for (int base = wv * 8; base < cnt; base += 128) {
            int ib = base + e8;
            if (ib < cnt) {
                uint ent = bd[ib];
                int src = ent & 0x1FFFF;
                int ld = ent >> 17;
                uint4 v = xr4[(long long)src * 8 + q8];
                if (q8 == 0) atomicAdd(&lh[ld], 1);
                float* ap = &acc[ld][q8 * 8];
                atomicAdd(&ap[0], __uint_as_float(v.x << 16));
                atomicAdd(&ap[1], __uint_as_float(v.x & 0xffff0000u));
                atomicAdd(&ap[2], __uint_as_float(v.y << 16));
                atomicAdd(&ap[3], __uint_as_float(v.y & 0xffff0000u));
                atomicAdd(&ap[4], __uint_as_float(v.z << 16));
                atomicAdd(&ap[5], __uint_as_float(v.z & 0xffff0000u));
                atomicAdd(&ap[6], __uint_as_float(v.w << 16));
                atomicAdd(&ap[7], __uint_as_float(v.w & 0xffff0000u));
            }
        }
    } else {
        // 4 edges per wave-iter; lane = edge(2b) x chunk(4b); row = 16 uint4
        int e4 = lane >> 4, q16 = lane & 15;
        const uint4* xf = (const uint4*)x;
        for (int base = wv * 4; base < cnt; base += 64) {
            int ib = base + e4;
            if (ib < cnt) {
                uint ent = bd[ib];
                int src = ent & 0x1FFFF;
                int ld = ent >> 17;
                uint4 v = xf[(long long)src * 16 + q16];
                if (q16 == 0) atomicAdd(&lh[ld], 1);
                float* ap = &acc[ld][q16 * 4];
                atomicAdd(&ap[0], __uint_as_float(v.x));
                atomicAdd(&ap[1], __uint_as_float(v.y));
                atomicAdd(&ap[2], __uint_as_float(v.z));
                atomicAdd(&ap[3], __uint_as_float(v.w));
            }
        }
    }
    __syncthreads();

    int g0 = b << 7;
    for (int i = t; i < 128 * 64; i += 1024) {
        int ld = i >> 6, ch = i & 63;
        int n = g0 + ld;
        if (n < N_NODES) {
            float inv = 1.0f / fmaxf((float)lh[ld], 1.0f);
            aggbuf[(long long)n * 64 + ch] = __float2bfloat16(acc[ld][ch] * inv);
        }
    }
    if (t < 128) {
        int n = g0 + t;
        if (n < N_NODES) deg_out[n] = lh[t];
    }
}

// ---------------- layer-1+2 GEMMs (MFMA, dense coalesced staging) ----------------
__global__ __launch_bounds__(256) void gemm1_kernel(
    const void* __restrict__ x, const bf16* __restrict__ aggbuf,
    const void* __restrict__ W1l, const void* __restrict__ b1l,
    const void* __restrict__ W1r, const void* __restrict__ W2l,
    const void* __restrict__ b2l, const void* __restrict__ W2r,
    bf16* __restrict__ zbuf, bf16* __restrict__ rbuf,
    const int* __restrict__ flags) {
    __shared__ __align__(16) unsigned short sW1t[64][136];
    __shared__ __align__(16) unsigned short sA[64][136];
    __shared__ __align__(16) unsigned short sW2t[64][72];
    __shared__ __align__(16) unsigned short sH[64][72];
    __shared__ float sB1[64];
    __shared__ float sB2[32];

    int isbf = flags[0];
    int t = threadIdx.x;
    int n0 = blockIdx.x * 64;

    for (int i = t; i < 64 * 128; i += 256) {
        int n = i & 63, k = i >> 6;
        unsigned short v;
        if (isbf)
            v = (k < 64) ? ((const unsigned short*)W1l)[k * 64 + n]
                         : ((const unsigned short*)W1r)[(k - 64) * 64 + n];
        else
            v = f2bits((k < 64) ? ((const float*)W1l)[k * 64 + n]
                                : ((const float*)W1r)[(k - 64) * 64 + n]);
        sW1t[n][k] = v;
    }
    for (int i = t; i < 64 * 64; i += 256) {
        int n = i & 63, k = i >> 6;
        unsigned short v;
        if (isbf)
            v = (n < 32) ? ((const unsigned short*)W2l)[k * 32 + n]
                         : ((const unsigned short*)W2r)[k * 32 + (n - 32)];
        else
            v = f2bits((n < 32) ? ((const float*)W2l)[k * 32 + n]
                                : ((const float*)W2r)[k * 32 + (n - 32)]);
        sW2t[n][k] = v;
    }
    if (t < 64) sB1[t] = get_f(b1l, t, isbf);
    if (t < 32) sB2[t] = get_f(b2l, t, isbf);

    const uint4* ag4 = (const uint4*)aggbuf;
    if (isbf) {
        const uint4* x4 = (const uint4*)x;
        for (int i = t; i < 64 * 16; i += 256) {
            int m = i >> 4, c = i & 15;
            int nn = min(n0 + m, N_NODES - 1);
            uint4 v = (c < 8) ? ag4[(long long)nn * 8 + c]
                              : x4[(long long)nn * 8 + (c - 8)];
            *(uint4*)&sA[m][c * 8] = v;
        }
    } else {
        for (int i = t; i < 64 * 8; i += 256) {
            int m = i >> 3, c = i & 7;
            int nn = min(n0 + m, N_NODES - 1);
            *(uint4*)&sA[m][c * 8] = ag4[(long long)nn * 8 + c];
        }
        const float* xf = (const float*)x;
        for (int i = t; i < 64 * 64; i += 256) {
            int m = i >> 6, c = i & 63;
            int nn = min(n0 + m, N_NODES - 1);
            sA[m][64 + c] = f2bf_bits(xf[(long long)nn * 64 + c]);
        }
    }
    __syncthreads();

    int w = t >> 6, lane = t & 63;
    int mbase = w * 16;
    int q = lane >> 4, r15 = lane & 15;
    f32x4 acc1[4] = {{0,0,0,0},{0,0,0,0},{0,0,0,0},{0,0,0,0}};
#pragma unroll
    for (int ks = 0; ks < 4; ks++) {
        bf16x8 afrag = *(const bf16x8*)&sA[mbase + r15][ks * 32 + q * 8];
#pragma unroll
        for (int nt = 0; nt < 4; nt++) {
            bf16x8 bfrag = *(const bf16x8*)&sW1t[nt * 16 + r15][ks * 32 + q * 8];
            acc1[nt] = __builtin_amdgcn_mfma_f32_16x16x32_bf16(afrag, bfrag, acc1[nt], 0, 0, 0);
        }
    }
#pragma unroll
    for (int nt = 0; nt < 4; nt++) {
        int col = nt * 16 + r15;
        float bias = sB1[col];
#pragma unroll
        for (int rr = 0; rr < 4; rr++) {
            int m = mbase + q * 4 + rr;
            sH[m][col] = f2bf_bits(fmaxf(acc1[nt][rr] + bias, 0.0f));
        }
    }
    __syncthreads();

    f32x4 acc2[4] = {{0,0,0,0},{0,0,0,0},{0,0,0,0},{0,0,0,0}};
#pragma unroll
    for (int ks = 0; ks < 2; ks++) {
        bf16x8 afrag = *(const bf16x8*)&sH[mbase + r15][ks * 32 + q * 8];
#pragma unroll
        for (int nt = 0; nt < 4; nt++) {
            bf16x8 bfrag = *(const bf16x8*)&sW2t[nt * 16 + r15][ks * 32 + q * 8];
            acc2[nt] = __builtin_amdgcn_mfma_f32_16x16x32_bf16(afrag, bfrag, acc2[nt], 0, 0, 0);
        }
    }
#pragma unroll
    for (int nt = 0; nt < 4; nt++) {
        int col = nt * 16 + r15;
#pragma unroll
        for (int rr = 0; rr < 4; rr++) {
            int m = mbase + q * 4 + rr;
            int n = n0 + m;
            if (n < N_NODES) {
                float v = acc2[nt][rr];
                if (col < 32)
                    zbuf[(long long)n * 32 + col] = __float2bfloat16(v);
                else
                    rbuf[(long long)n * 32 + (col - 32)] = __float2bfloat16(v + sB2[col - 32]);
            }
        }
    }
}

// ---------------- layer-2 aggregation + final combine (per-bucket scatter) ----------------
// z rows are 64 B (4 uint4): 16 edges per wave-iter.
__global__ __launch_bounds__(1024) void aggZ_kernel(
    const bf16* __restrict__ z, const bf16* __restrict__ rbuf,
    const int* __restrict__ bucket_cnt, const uint* __restrict__ bucket_data,
    const int* __restrict__ deg, void* __restrict__ out,
    const int* __restrict__ flags) {
    __shared__ float acc[128][33];  // bank=(ld+8s+j)%32
    int b = blockIdx.x;
    int t = threadIdx.x;
    int isbf = flags[0];
    int cnt = min(bucket_cnt[b], BKT_CAP);
    const uint* bd = bucket_data + (long long)b * BKT_CAP;

    float* accf = &acc[0][0];
    for (int i = t; i < 128 * 33; i += 1024) accf[i] = 0.0f;
    __syncthreads();

    int wv = t >> 6, lane = t & 63;
    int e4 = lane >> 2, q4 = lane & 3;
    const uint4* zr = (const uint4*)z;
    for (int base = wv * 16; base < cnt; base += 256) {
        int ib = base + e4;
        if (ib < cnt) {
            uint ent = bd[ib];
            int src = ent & 0x1FFFF;
            int ld = ent >> 17;
            uint4 v = zr[(long long)src * 4 + q4];
            float* ap = &acc[ld][q4 * 8];
            atomicAdd(&ap[0], __uint_as_float(v.x << 16));
            atomicAdd(&ap[1], __uint_as_float(v.x & 0xffff0000u));
            atomicAdd(&ap[2], __uint_as_float(v.y << 16));
            atomicAdd(&ap[3], __uint_as_float(v.y & 0xffff0000u));
            atomicAdd(&ap[4], __uint_as_float(v.z << 16));
            atomicAdd(&ap[5], __uint_as_float(v.z & 0xffff0000u));
            atomicAdd(&ap[6], __uint_as_float(v.w << 16));
            atomicAdd(&ap[7], __uint_as_float(v.w & 0xffff0000u));
        }
    }
    __syncthreads();

    int g0 = b << 7;
    for (int i = t; i < 128 * 32; i += 1024) {
        int ld = i >> 5, c = i & 31;
        int n = g0 + ld;
        if (n < N_NODES) {
            float inv = 1.0f / fmaxf((float)deg[n], 1.0f);
            float val = acc[ld][c] * inv + b2f(rbuf[(long long)n * 32 + c]);
            if (isbf)
                ((bf16*)out)[(long long)n * 32 + c] = __float2bfloat16(val);
            else
                ((float*)out)[(long long)n * 32 + c] = val;
        }
    }
}

extern "C" void kernel_launch(void* const* d_in, const int* in_sizes, int n_in,
                              void* d_out, int out_size, void* d_ws, size_t ws_size,
                              hipStream_t stream) {
    const void* x = d_in[0];
    const void* ei = d_in[1];  // [2, E]: src = [0,E), dst = [E,2E)
    const void* W1l = d_in[2];
    const void* b1l = d_in[3];
    const void* W1r = d_in[4];
    const void* W2l = d_in[5];
    const void* b2l = d_in[6];
    const void* W2r = d_in[7];

    // workspace layout (~42.9 MB)
    char* ws = (char*)d_ws;
    uint* bucket_data = (uint*)ws;                // NBKT*BKT_CAP u32 = 16.8 MB
    bf16* aggbuf = (bf16*)(ws + 16816192);        // N*64 bf16 = 12.8 MB
    bf16* zbuf = (bf16*)(ws + 29616192);          // N*32 bf16 = 6.4 MB
    bf16* rbuf = (bf16*)(ws + 36016192);          // N*32 bf16 = 6.4 MB
    int* deg = (int*)(ws + 42416192);             // N i32 = 0.4 MB
    int* bucket_cursor = (int*)(ws + 42816192);   // NBKT i32
    int* flags = (int*)(ws + 42819392);           // 2 i32

    hipMemsetAsync(bucket_cursor, 0, NBKT * 4, stream);

    detect_kernel<<<1, 64, 0, stream>>>(x, ei, flags);
    scatterA_kernel<<<NBKT, 256, 0, stream>>>(ei, bucket_cursor, bucket_data, flags);
    aggX_kernel<<<NBKT, 1024, 0, stream>>>(x, bucket_cursor, bucket_data, aggbuf,
                                           deg, flags);
    gemm1_kernel<<<1563, 256, 0, stream>>>(x, aggbuf, W1l, b1l, W1r, W2l, b2l,
                                           W2r, zbuf, rbuf, flags);
    aggZ_kernel<<<NBKT, 1024, 0, stream>>>(zbuf, rbuf, bucket_cursor, bucket_data,
                                           deg, d_out, flags);
}

// Round 9
// 356.677 us; speedup vs baseline: 6.1612x; 6.1612x over previous
//
#include <hip/hip_runtime.h>
#include <hip/hip_bf16.h>

#define N_NODES 100000
#define N_EDGES 3200000
#define NBKT 391      // ceil(N_NODES/256): bucket = dst>>8
#define BKT_CAP 10240 // avg 8184 edges/bucket, +23 sigma margin

typedef __hip_bfloat16 bf16;
typedef unsigned int uint;
typedef __attribute__((ext_vector_type(8))) short bf16x8;
typedef __attribute__((ext_vector_type(4))) float f32x4;

__device__ __forceinline__ float b2f(bf16 v) { return __bfloat162float(v); }

__device__ __forceinline__ float bits2f(unsigned short w) {
    union { unsigned short u; bf16 b; } c;
    c.u = w;
    return __bfloat162float(c.b);
}
__device__ __forceinline__ unsigned short f2bits(float f) {  // truncate
    return (unsigned short)(__float_as_uint(f) >> 16);
}
__device__ __forceinline__ unsigned short f2bf_bits(float f) {  // RNE
    bf16 b = __float2bfloat16(f);
    unsigned short u;
    __builtin_memcpy(&u, &b, 2);
    return u;
}

// runtime dtype accessors -------------------------------------------------
__device__ __forceinline__ int get_idx(const void* ei, long long pos, int is64) {
    if (is64) return (int)((const long long*)ei)[pos];
    return ((const int*)ei)[pos];
}
__device__ __forceinline__ float get_f(const void* p, long long pos, int isbf) {
    if (isbf) return b2f(((const bf16*)p)[pos]);
    return ((const float*)p)[pos];
}

// ---------------- dtype detection (1 wave) ----------------
__global__ void detect_kernel(const void* __restrict__ x,
                              const void* __restrict__ ei,
                              int* __restrict__ flags) {
    int lane = threadIdx.x;  // 64 threads
    const unsigned short* xw = (const unsigned short*)x;
    float v = bits2f(xw[2 * lane]);
    bool plaus = (v == v) && fabsf(v) > 1e-3f && fabsf(v) < 1e2f;
    unsigned long long m1 = __ballot(plaus);
    const int* iw = (const int*)ei;
    bool z = (iw[2 * lane + 1] == 0);
    unsigned long long m2 = __ballot(z);
    if (lane == 0) {
        flags[0] = (__popcll(m1) >= 32) ? 1 : 0;
        flags[1] = (__popcll(m2) == 64) ? 1 : 0;
    }
}

// ---------------- pass A: bucket edges by dst>>8 ----------------
// dst cached in registers across phases: phase 2 reads only the src half.
__global__ __launch_bounds__(256) void scatterA_kernel(
    const void* __restrict__ ei, int* __restrict__ bucket_cursor,
    uint* __restrict__ bucket_data, const int* __restrict__ flags) {
    __shared__ int lhist[NBKT];
    __shared__ int lbase[NBKT];
    int is64 = flags[1];
    int t = threadIdx.x;
    int chunk0 = blockIdx.x * 8192;
    int dreg[32];

    for (int i = t; i < NBKT; i += 256) lhist[i] = 0;
    __syncthreads();
#pragma unroll
    for (int j = 0; j < 32; j++) {
        int e = chunk0 + j * 256 + t;
        int d = -1;
        if (e < N_EDGES) {
            d = get_idx(ei, (long long)N_EDGES + e, is64);
            atomicAdd(&lhist[d >> 8], 1);
        }
        dreg[j] = d;
    }
    __syncthreads();
    for (int i = t; i < NBKT; i += 256) {
        int c = lhist[i];
        lbase[i] = c ? atomicAdd(&bucket_cursor[i], c) : 0;
        lhist[i] = 0;  // reuse as local cursor
    }
    __syncthreads();
#pragma unroll
    for (int j = 0; j < 32; j++) {
        int e = chunk0 + j * 256 + t;
        int d = dreg[j];
        if (d >= 0) {
            int s = get_idx(ei, e, is64);
            int b = d >> 8;
            int o = lbase[b] + atomicAdd(&lhist[b], 1);
            if (o < BKT_CAP)
                bucket_data[(long long)b * BKT_CAP + o] = ((uint)(d & 255) << 17) | (uint)s;
        }
    }
}

// ---------------- scan bucket counts -> bucket base ----------------
__global__ void scanBuckets_kernel(const int* __restrict__ cnt,
                                   int* __restrict__ base) {
    __shared__ int buf[512];
    int t = threadIdx.x;  // 512 threads
    int v = (t < NBKT) ? cnt[t] : 0;
    buf[t] = v;
    __syncthreads();
    for (int off = 1; off < 512; off <<= 1) {
        int add = (t >= off) ? buf[t - off] : 0;
        __syncthreads();
        buf[t] += add;
        __syncthreads();
    }
    if (t < NBKT) base[t] = buf[t] - v;  // exclusive
}

// ---------------- pass B: per-bucket CSR build ----------------
__global__ __launch_bounds__(256) void csrB_kernel(
    const int* __restrict__ bucket_cnt, const int* __restrict__ bucket_base,
    const uint* __restrict__ bucket_data, int* __restrict__ csr_src,
    int* __restrict__ row_start) {
    __shared__ int lh[256];
    __shared__ int buf[256];
    int b = blockIdx.x;
    int t = threadIdx.x;
    int cnt = bucket_cnt[b];
    if (cnt > BKT_CAP) cnt = BKT_CAP;
    int base = bucket_base[b];
    const uint* bd = bucket_data + (long long)b * BKT_CAP;

    lh[t] = 0;
    __syncthreads();
    for (int i = t; i < cnt; i += 256) atomicAdd(&lh[bd[i] >> 17], 1);
    __syncthreads();
    int v = lh[t];
    buf[t] = v;
    __syncthreads();
    for (int off = 1; off < 256; off <<= 1) {
        int add = (t >= off) ? buf[t - off] : 0;
        __syncthreads();
        buf[t] += add;
        __syncthreads();
    }
    int excl = buf[t] - v;
    int g = (b << 8) + t;
    if (g < N_NODES) row_start[g] = base + excl;
    lh[t] = excl;  // reuse as local cursor
    __syncthreads();
    for (int i = t; i < cnt; i += 256) {
        uint e = bd[i];
        int o = atomicAdd(&lh[e >> 17], 1);
        csr_src[base + o] = (int)(e & 0x1FFFFu);
    }
    if (b == 0 && t == 0) row_start[N_NODES] = N_EDGES;
}

// ---------------- layer-1 gather (no LDS, max occupancy) ----------------
// one wave per node (grid-stride): agg = mean of x[src] rows -> aggbuf (bf16)
__global__ __launch_bounds__(256) void gather1_kernel(
    const void* __restrict__ x, const int* __restrict__ row_start,
    const int* __restrict__ csr_src, bf16* __restrict__ aggbuf,
    const int* __restrict__ flags) {
    int isbf = flags[0];
    int t = threadIdx.x;
    int lane = t & 63;
    int gw = (blockIdx.x * 256 + t) >> 6;
    int nw = (gridDim.x * 256) >> 6;
    int e8 = lane >> 3, q8 = lane & 7;    // bf16: 8 edges x 8 chunks
    int e4 = lane >> 4, q16 = lane & 15;  // fp32: 4 edges x 16 chunks
    const uint4* xr4 = (const uint4*)x;

    for (int n = gw; n < N_NODES; n += nw) {
        int start = row_start[n];
        int end = row_start[n + 1];
        int dg = end - start;
        float acc[8] = {0, 0, 0, 0, 0, 0, 0, 0};
        float av = 0.0f;
        if (isbf) {
            for (int base = start; base < end; base += 32) {
                int i0 = base + e8, i1 = i0 + 8, i2 = i0 + 16, i3 = i0 + 24;
                int s0 = (i0 < end) ? csr_src[i0] : -1;
                int s1 = (i1 < end) ? csr_src[i1] : -1;
                int s2 = (i2 < end) ? csr_src[i2] : -1;
                int s3 = (i3 < end) ? csr_src[i3] : -1;
                uint4 v0 = {0,0,0,0}, v1 = {0,0,0,0}, v2 = {0,0,0,0}, v3 = {0,0,0,0};
                if (s0 >= 0) v0 = xr4[s0 * 8 + q8];
                if (s1 >= 0) v1 = xr4[s1 * 8 + q8];
                if (s2 >= 0) v2 = xr4[s2 * 8 + q8];
                if (s3 >= 0) v3 = xr4[s3 * 8 + q8];
                acc[0] += __uint_as_float(v0.x << 16) + __uint_as_float(v1.x << 16)
                        + __uint_as_float(v2.x << 16) + __uint_as_float(v3.x << 16);
                acc[1] += __uint_as_float(v0.x & 0xffff0000u) + __uint_as_float(v1.x & 0xffff0000u)
                        + __uint_as_float(v2.x & 0xffff0000u) + __uint_as_float(v3.x & 0xffff0000u);
                acc[2] += __uint_as_float(v0.y << 16) + __uint_as_float(v1.y << 16)
                        + __uint_as_float(v2.y << 16) + __uint_as_float(v3.y << 16);
                acc[3] += __uint_as_float(v0.y & 0xffff0000u) + __uint_as_float(v1.y & 0xffff0000u)
                        + __uint_as_float(v2.y & 0xffff0000u) + __uint_as_float(v3.y & 0xffff0000u);
                acc[4] += __uint_as_float(v0.z << 16) + __uint_as_float(v1.z << 16)
                        + __uint_as_float(v2.z << 16) + __uint_as_float(v3.z << 16);
                acc[5] += __uint_as_float(v0.z & 0xffff0000u) + __uint_as_float(v1.z & 0xffff0000u)
                        + __uint_as_float(v2.z & 0xffff0000u) + __uint_as_float(v3.z & 0xffff0000u);
                acc[6] += __uint_as_float(v0.w << 16) + __uint_as_float(v1.w << 16)
                        + __uint_as_float(v2.w << 16) + __uint_as_float(v3.w << 16);
                acc[7] += __uint_as_float(v0.w & 0xffff0000u) + __uint_as_float(v1.w & 0xffff0000u)
                        + __uint_as_float(v2.w & 0xffff0000u) + __uint_as_float(v3.w & 0xffff0000u);
            }
#pragma unroll
            for (int mm = 8; mm <= 32; mm <<= 1)
#pragma unroll
                for (int k = 0; k < 8; k++) acc[k] += __shfl_xor(acc[k], mm, 64);
#pragma unroll
            for (int k = 0; k < 8; k++) {
                float v = __shfl(acc[k], lane >> 3, 64);
                av = ((lane & 7) == k) ? v : av;
            }
        } else {
            const uint4* xf = (const uint4*)x;  // fp32 row = 16 uint4
            for (int base = start; base < end; base += 16) {
                int i0 = base + e4, i1 = i0 + 4, i2 = i0 + 8, i3 = i0 + 12;
                int s0 = (i0 < end) ? csr_src[i0] : -1;
                int s1 = (i1 < end) ? csr_src[i1] : -1;
                int s2 = (i2 < end) ? csr_src[i2] : -1;
                int s3 = (i3 < end) ? csr_src[i3] : -1;
                uint4 v0 = {0,0,0,0}, v1 = {0,0,0,0}, v2 = {0,0,0,0}, v3 = {0,0,0,0};
                if (s0 >= 0) v0 = xf[s0 * 16 + q16];
                if (s1 >= 0) v1 = xf[s1 * 16 + q16];
                if (s2 >= 0) v2 = xf[s2 * 16 + q16];
                if (s3 >= 0) v3 = xf[s3 * 16 + q16];
                acc[0] += __uint_as_float(v0.x) + __uint_as_float(v1.x)
                        + __uint_as_float(v2.x) + __uint_as_float(v3.x);
                acc[1] += __uint_as_float(v0.y) + __uint_as_float(v1.y)
                        + __uint_as_float(v2.y) + __uint_as_float(v3.y);
                acc[2] += __uint_as_float(v0.z) + __uint_as_float(v1.z)
                        + __uint_as_float(v2.z) + __uint_as_float(v3.z);
                acc[3] += __uint_as_float(v0.w) + __uint_as_float(v1.w)
                        + __uint_as_float(v2.w) + __uint_as_float(v3.w);
            }
#pragma unroll
            for (int mm = 16; mm <= 32; mm <<= 1)
#pragma unroll
                for (int k = 0; k < 4; k++) acc[k] += __shfl_xor(acc[k], mm, 64);
#pragma unroll
            for (int k = 0; k < 4; k++) {
                float v = __shfl(acc[k], lane >> 2, 64);
                av = ((lane & 3) == k) ? v : av;
            }
        }
        av *= 1.0f / fmaxf((float)dg, 1.0f);
        aggbuf[(long long)n * 64 + lane] = __float2bfloat16(av);
    }
}

// ---------------- layer-1+2 GEMMs (MFMA, dense coalesced staging) ----------------
__global__ __launch_bounds__(256) void gemm1_kernel(
    const void* __restrict__ x, const bf16* __restrict__ aggbuf,
    const void* __restrict__ W1l, const void* __restrict__ b1l,
    const void* __restrict__ W1r, const void* __restrict__ W2l,
    const void* __restrict__ b2l, const void* __restrict__ W2r,
    bf16* __restrict__ zbuf, bf16* __restrict__ rbuf,
    const int* __restrict__ flags) {
    __shared__ __align__(16) unsigned short sW1t[64][136];
    __shared__ __align__(16) unsigned short sA[64][136];
    __shared__ __align__(16) unsigned short sW2t[64][72];
    __shared__ __align__(16) unsigned short sH[64][72];
    __shared__ float sB1[64];
    __shared__ float sB2[32];

    int isbf = flags[0];
    int t = threadIdx.x;
    int n0 = blockIdx.x * 64;

    for (int i = t; i < 64 * 128; i += 256) {
        int n = i & 63, k = i >> 6;
        unsigned short v;
        if (isbf)
            v = (k < 64) ? ((const unsigned short*)W1l)[k * 64 + n]
                         : ((const unsigned short*)W1r)[(k - 64) * 64 + n];
        else
            v = f2bits((k < 64) ? ((const float*)W1l)[k * 64 + n]
                                : ((const float*)W1r)[(k - 64) * 64 + n]);
        sW1t[n][k] = v;
    }
    for (int i = t; i < 64 * 64; i += 256) {
        int n = i & 63, k = i >> 6;
        unsigned short v;
        if (isbf)
            v = (n < 32) ? ((const unsigned short*)W2l)[k * 32 + n]
                         : ((const unsigned short*)W2r)[k * 32 + (n - 32)];
        else
            v = f2bits((n < 32) ? ((const float*)W2l)[k * 32 + n]
                                : ((const float*)W2r)[k * 32 + (n - 32)]);
        sW2t[n][k] = v;
    }
    if (t < 64) sB1[t] = get_f(b1l, t, isbf);
    if (t < 32) sB2[t] = get_f(b2l, t, isbf);

    const uint4* ag4 = (const uint4*)aggbuf;
    if (isbf) {
        const uint4* x4 = (const uint4*)x;
        for (int i = t; i < 64 * 16; i += 256) {
            int m = i >> 4, c = i & 15;
            int nn = min(n0 + m, N_NODES - 1);
            uint4 v = (c < 8) ? ag4[(long long)nn * 8 + c]
                              : x4[(long long)nn * 8 + (c - 8)];
            *(uint4*)&sA[m][c * 8] = v;
        }
    } else {
        for (int i = t; i < 64 * 8; i += 256) {
            int m = i >> 3, c = i & 7;
            int nn = min(n0 + m, N_NODES - 1);
            *(uint4*)&sA[m][c * 8] = ag4[(long long)nn * 8 + c];
        }
        const float* xf = (const float*)x;
        for (int i = t; i < 64 * 64; i += 256) {
            int m = i >> 6, c = i & 63;
            int nn = min(n0 + m, N_NODES - 1);
            sA[m][64 + c] = f2bf_bits(xf[(long long)nn * 64 + c]);
        }
    }
    __syncthreads();

    int w = t >> 6, lane = t & 63;
    int mbase = w * 16;
    int q = lane >> 4, r15 = lane & 15;
    f32x4 acc1[4] = {{0,0,0,0},{0,0,0,0},{0,0,0,0},{0,0,0,0}};
#pragma unroll
    for (int ks = 0; ks < 4; ks++) {
        bf16x8 afrag = *(const bf16x8*)&sA[mbase + r15][ks * 32 + q * 8];
#pragma unroll
        for (int nt = 0; nt < 4; nt++) {
            bf16x8 bfrag = *(const bf16x8*)&sW1t[nt * 16 + r15][ks * 32 + q * 8];
            acc1[nt] = __builtin_amdgcn_mfma_f32_16x16x32_bf16(afrag, bfrag, acc1[nt], 0, 0, 0);
        }
    }
#pragma unroll
    for (int nt = 0; nt < 4; nt++) {
        int col = nt * 16 + r15;
        float bias = sB1[col];
#pragma unroll
        for (int rr = 0; rr < 4; rr++) {
            int m = mbase + q * 4 + rr;
            sH[m][col] = f2bf_bits(fmaxf(acc1[nt][rr] + bias, 0.0f));
        }
    }
    __syncthreads();

    f32x4 acc2[4] = {{0,0,0,0},{0,0,0,0},{0,0,0,0},{0,0,0,0}};
#pragma unroll
    for (int ks = 0; ks < 2; ks++) {
        bf16x8 afrag = *(const bf16x8*)&sH[mbase + r15][ks * 32 + q * 8];
#pragma unroll
        for (int nt = 0; nt < 4; nt++) {
            bf16x8 bfrag = *(const bf16x8*)&sW2t[nt * 16 + r15][ks * 32 + q * 8];
            acc2[nt] = __builtin_amdgcn_mfma_f32_16x16x32_bf16(afrag, bfrag, acc2[nt], 0, 0, 0);
        }
    }
#pragma unroll
    for (int nt = 0; nt < 4; nt++) {
        int col = nt * 16 + r15;
#pragma unroll
        for (int rr = 0; rr < 4; rr++) {
            int m = mbase + q * 4 + rr;
            int n = n0 + m;
            if (n < N_NODES) {
                float v = acc2[nt][rr];
                if (col < 32)
                    zbuf[(long long)n * 32 + col] = __float2bfloat16(v);
                else
                    rbuf[(long long)n * 32 + (col - 32)] = __float2bfloat16(v + sB2[col - 32]);
            }
        }
    }
}

// ---------------- layer-2: gather z, 2 nodes per wave (4 loads in flight) ----------------
__global__ void node2_kernel(const int* __restrict__ row_start,
                             const int* __restrict__ csr_src,
                             const bf16* __restrict__ z,
                             const bf16* __restrict__ rbuf,
                             void* __restrict__ out,
                             const int* __restrict__ flags) {
    int isbf = flags[0];
    int t = threadIdx.x;
    int lane = t & 63;
    int e = lane >> 2, q = lane & 3;  // 16 edges x 4 chunks per load
    int gw = (blockIdx.x * blockDim.x + t) >> 6;
    int nwaves = (gridDim.x * blockDim.x) >> 6;
    const uint4* zr = (const uint4*)z;

    for (int p = gw; p * 2 < N_NODES; p += nwaves) {
        int na = p * 2, nb = p * 2 + 1;  // N even: nb < N always
        int sa = row_start[na], ea = row_start[na + 1];
        int sb = row_start[nb], eb = row_start[nb + 1];
        float accA[8] = {0, 0, 0, 0, 0, 0, 0, 0};
        float accB[8] = {0, 0, 0, 0, 0, 0, 0, 0};
        int da = ea - sa, db = eb - sb;
        int maxd = max(da, db);
        for (int off = 0; off < maxd; off += 16) {
            int ia = sa + off + e, ib = sb + off + e;
            int s0 = (ia < ea) ? csr_src[ia] : -1;
            int s1 = (ib < eb) ? csr_src[ib] : -1;
            uint4 v0 = {0, 0, 0, 0}, v1 = {0, 0, 0, 0};
            if (s0 >= 0) v0 = zr[s0 * 4 + q];
            if (s1 >= 0) v1 = zr[s1 * 4 + q];
            accA[0] += __uint_as_float(v0.x << 16);
            accA[1] += __uint_as_float(v0.x & 0xffff0000u);
            accA[2] += __uint_as_float(v0.y << 16);
            accA[3] += __uint_as_float(v0.y & 0xffff0000u);
            accA[4] += __uint_as_float(v0.z << 16);
            accA[5] += __uint_as_float(v0.z & 0xffff0000u);
            accA[6] += __uint_as_float(v0.w << 16);
            accA[7] += __uint_as_float(v0.w & 0xffff0000u);
            accB[0] += __uint_as_float(v1.x << 16);
            accB[1] += __uint_as_float(v1.x & 0xffff0000u);
            accB[2] += __uint_as_float(v1.y << 16);
            accB[3] += __uint_as_float(v1.y & 0xffff0000u);
            accB[4] += __uint_as_float(v1.z << 16);
            accB[5] += __uint_as_float(v1.z & 0xffff0000u);
            accB[6] += __uint_as_float(v1.w << 16);
            accB[7] += __uint_as_float(v1.w & 0xffff0000u);
        }
#pragma unroll
        for (int m = 4; m <= 32; m <<= 1)
#pragma unroll
            for (int k = 0; k < 8; k++) {
                accA[k] += __shfl_xor(accA[k], m, 64);
                accB[k] += __shfl_xor(accB[k], m, 64);
            }
        // channel c = q*8+k: lane c wants acc[c&7] from lane (c>>3)
        float svA = 0.0f, svB = 0.0f;
#pragma unroll
        for (int k = 0; k < 8; k++) {
            float vA = __shfl(accA[k], lane >> 3, 64);
            float vB = __shfl(accB[k], lane >> 3, 64);
            svA = ((lane & 7) == k) ? vA : svA;
            svB = ((lane & 7) == k) ? vB : svB;
        }
        if (lane < 32) {
            float invA = 1.0f / fmaxf((float)da, 1.0f);
            float invB = 1.0f / fmaxf((float)db, 1.0f);
            float valA = svA * invA + b2f(rbuf[(long long)na * 32 + lane]);
            float valB = svB * invB + b2f(rbuf[(long long)nb * 32 + lane]);
            if (isbf) {
                ((bf16*)out)[(long long)na * 32 + lane] = __float2bfloat16(valA);
                ((bf16*)out)[(long long)nb * 32 + lane] = __float2bfloat16(valB);
            } else {
                ((float*)out)[(long long)na * 32 + lane] = valA;
                ((float*)out)[(long long)nb * 32 + lane] = valB;
            }
        }
    }
}

extern "C" void kernel_launch(void* const* d_in, const int* in_sizes, int n_in,
                              void* d_out, int out_size, void* d_ws, size_t ws_size,
                              hipStream_t stream) {
    const void* x = d_in[0];
    const void* ei = d_in[1];  // [2, E]: src = [0,E), dst = [E,2E)
    const void* W1l = d_in[2];
    const void* b1l = d_in[3];
    const void* W1r = d_in[4];
    const void* W2l = d_in[5];
    const void* b2l = d_in[6];
    const void* W2r = d_in[7];

    // workspace layout (~42 MB). aggbuf ALIASES bucket_data (dead after csrB).
    char* ws = (char*)d_ws;
    uint* bucket_data = (uint*)ws;                    // NBKT*BKT_CAP u32 = 16.0 MB
    bf16* aggbuf = (bf16*)ws;                         // N*64 bf16 = 12.8 MB (alias)
    int* csr_src = (int*)(ws + 16015424);             // E i32 = 12.8 MB
    int* row_start = (int*)(ws + 28815424);           // N+1 i32
    int* bucket_cursor = (int*)(ws + 29215488);       // NBKT i32
    int* bucket_base = (int*)(ws + 29217088);         // NBKT i32
    bf16* zbuf = (bf16*)(ws + 29218688);              // N*32 bf16 = 6.4 MB
    bf16* rbuf = (bf16*)(ws + 35618688);              // N*32 bf16 = 6.4 MB
    int* flags = (int*)(ws + 42018688);               // 2 i32

    hipMemsetAsync(bucket_cursor, 0, NBKT * 4, stream);

    detect_kernel<<<1, 64, 0, stream>>>(x, ei, flags);
    scatterA_kernel<<<NBKT, 256, 0, stream>>>(ei, bucket_cursor, bucket_data, flags);
    scanBuckets_kernel<<<1, 512, 0, stream>>>(bucket_cursor, bucket_base);
    csrB_kernel<<<NBKT, 256, 0, stream>>>(bucket_cursor, bucket_base, bucket_data,
                                          csr_src, row_start);
    gather1_kernel<<<6250, 256, 0, stream>>>(x, row_start, csr_src, aggbuf, flags);
    gemm1_kernel<<<1563, 256, 0, stream>>>(x, aggbuf, W1l, b1l, W1r, W2l, b2l,
                                           W2r, zbuf, rbuf, flags);
    node2_kernel<<<8192, 256, 0, stream>>>(row_start, csr_src, zbuf, rbuf, d_out,
                                           flags);
}

// Round 10
// 355.141 us; speedup vs baseline: 6.1878x; 1.0043x over previous
//
#include <hip/hip_runtime.h>
#include <hip/hip_bf16.h>

#define N_NODES 100000
#define N_EDGES 3200000
#define NBKT 391      // ceil(N_NODES/256): bucket = dst>>8
#define BKT_CAP 10240 // avg 8184 edges/bucket, +23 sigma margin

typedef __hip_bfloat16 bf16;
typedef unsigned int uint;
typedef __attribute__((ext_vector_type(8))) short bf16x8;
typedef __attribute__((ext_vector_type(4))) float f32x4;

__device__ __forceinline__ float b2f(bf16 v) { return __bfloat162float(v); }

__device__ __forceinline__ float bits2f(unsigned short w) {
    union { unsigned short u; bf16 b; } c;
    c.u = w;
    return __bfloat162float(c.b);
}
__device__ __forceinline__ unsigned short f2bits(float f) {  // truncate
    return (unsigned short)(__float_as_uint(f) >> 16);
}
__device__ __forceinline__ unsigned short f2bf_bits(float f) {  // RNE
    bf16 b = __float2bfloat16(f);
    unsigned short u;
    __builtin_memcpy(&u, &b, 2);
    return u;
}

// runtime dtype accessors -------------------------------------------------
__device__ __forceinline__ int get_idx(const void* ei, long long pos, int is64) {
    if (is64) return (int)((const long long*)ei)[pos];
    return ((const int*)ei)[pos];
}
__device__ __forceinline__ float get_f(const void* p, long long pos, int isbf) {
    if (isbf) return b2f(((const bf16*)p)[pos]);
    return ((const float*)p)[pos];
}

// ---------------- dtype detection (1 wave) ----------------
__global__ void detect_kernel(const void* __restrict__ x,
                              const void* __restrict__ ei,
                              int* __restrict__ flags) {
    int lane = threadIdx.x;  // 64 threads
    const unsigned short* xw = (const unsigned short*)x;
    float v = bits2f(xw[2 * lane]);
    bool plaus = (v == v) && fabsf(v) > 1e-3f && fabsf(v) < 1e2f;
    unsigned long long m1 = __ballot(plaus);
    const int* iw = (const int*)ei;
    bool z = (iw[2 * lane + 1] == 0);
    unsigned long long m2 = __ballot(z);
    if (lane == 0) {
        flags[0] = (__popcll(m1) >= 32) ? 1 : 0;
        flags[1] = (__popcll(m2) == 64) ? 1 : 0;
    }
}

// ---------------- pass A: bucket edges by dst>>8 ----------------
__global__ __launch_bounds__(256) void scatterA_kernel(
    const void* __restrict__ ei, int* __restrict__ bucket_cursor,
    uint* __restrict__ bucket_data, const int* __restrict__ flags) {
    __shared__ int lhist[NBKT];
    __shared__ int lbase[NBKT];
    int is64 = flags[1];
    int t = threadIdx.x;
    int chunk0 = blockIdx.x * 8192;
    int dreg[32];

    for (int i = t; i < NBKT; i += 256) lhist[i] = 0;
    __syncthreads();
#pragma unroll
    for (int j = 0; j < 32; j++) {
        int e = chunk0 + j * 256 + t;
        int d = -1;
        if (e < N_EDGES) {
            d = get_idx(ei, (long long)N_EDGES + e, is64);
            atomicAdd(&lhist[d >> 8], 1);
        }
        dreg[j] = d;
    }
    __syncthreads();
    for (int i = t; i < NBKT; i += 256) {
        int c = lhist[i];
        lbase[i] = c ? atomicAdd(&bucket_cursor[i], c) : 0;
        lhist[i] = 0;  // reuse as local cursor
    }
    __syncthreads();
#pragma unroll
    for (int j = 0; j < 32; j++) {
        int e = chunk0 + j * 256 + t;
        int d = dreg[j];
        if (d >= 0) {
            int s = get_idx(ei, e, is64);
            int b = d >> 8;
            int o = lbase[b] + atomicAdd(&lhist[b], 1);
            if (o < BKT_CAP)
                bucket_data[(long long)b * BKT_CAP + o] = ((uint)(d & 255) << 17) | (uint)s;
        }
    }
}

// ---------------- scan bucket counts -> bucket base ----------------
__global__ void scanBuckets_kernel(const int* __restrict__ cnt,
                                   int* __restrict__ base) {
    __shared__ int buf[512];
    int t = threadIdx.x;  // 512 threads
    int v = (t < NBKT) ? cnt[t] : 0;
    buf[t] = v;
    __syncthreads();
    for (int off = 1; off < 512; off <<= 1) {
        int add = (t >= off) ? buf[t - off] : 0;
        __syncthreads();
        buf[t] += add;
        __syncthreads();
    }
    if (t < NBKT) base[t] = buf[t] - v;  // exclusive
}

// ---------------- pass B: per-bucket CSR build ----------------
__global__ __launch_bounds__(256) void csrB_kernel(
    const int* __restrict__ bucket_cnt, const int* __restrict__ bucket_base,
    const uint* __restrict__ bucket_data, int* __restrict__ csr_src,
    int* __restrict__ row_start) {
    __shared__ int lh[256];
    __shared__ int buf[256];
    int b = blockIdx.x;
    int t = threadIdx.x;
    int cnt = bucket_cnt[b];
    if (cnt > BKT_CAP) cnt = BKT_CAP;
    int base = bucket_base[b];
    const uint* bd = bucket_data + (long long)b * BKT_CAP;

    lh[t] = 0;
    __syncthreads();
    for (int i = t; i < cnt; i += 256) atomicAdd(&lh[bd[i] >> 17], 1);
    __syncthreads();
    int v = lh[t];
    buf[t] = v;
    __syncthreads();
    for (int off = 1; off < 256; off <<= 1) {
        int add = (t >= off) ? buf[t - off] : 0;
        __syncthreads();
        buf[t] += add;
        __syncthreads();
    }
    int excl = buf[t] - v;
    int g = (b << 8) + t;
    if (g < N_NODES) row_start[g] = base + excl;
    lh[t] = excl;  // reuse as local cursor
    __syncthreads();
    for (int i = t; i < cnt; i += 256) {
        uint e = bd[i];
        int o = atomicAdd(&lh[e >> 17], 1);
        csr_src[base + o] = (int)(e & 0x1FFFFu);
    }
    if (b == 0 && t == 0) row_start[N_NODES] = N_EDGES;
}

// ---------------- layer-1 gather: 2 nodes/wave, 8 loads in flight ----------------
__global__ __launch_bounds__(256) void gather1_kernel(
    const void* __restrict__ x, const int* __restrict__ row_start,
    const int* __restrict__ csr_src, bf16* __restrict__ aggbuf,
    const int* __restrict__ flags) {
    int isbf = flags[0];
    int t = threadIdx.x;
    int lane = t & 63;
    int gw = (blockIdx.x * 256 + t) >> 6;
    int nw = (gridDim.x * 256) >> 6;
    int e8 = lane >> 3, q8 = lane & 7;    // bf16: 8 edges x 8 chunks
    int e4 = lane >> 4, q16 = lane & 15;  // fp32: 4 edges x 16 chunks
    const uint4* xr4 = (const uint4*)x;

    for (int p = gw; p * 2 < N_NODES; p += nw) {
        int na = p * 2, nb = p * 2 + 1;
        int sa = row_start[na], ea = row_start[na + 1];
        int sb = row_start[nb], eb = row_start[nb + 1];
        int da = ea - sa, db = eb - sb;
        int maxd = max(da, db);
        float accA[8] = {0, 0, 0, 0, 0, 0, 0, 0};
        float accB[8] = {0, 0, 0, 0, 0, 0, 0, 0};
        float avA = 0.0f, avB = 0.0f;
        if (isbf) {
            for (int off = 0; off < maxd; off += 32) {
                int iA0 = sa + off + e8, iA1 = iA0 + 8, iA2 = iA0 + 16, iA3 = iA0 + 24;
                int iB0 = sb + off + e8, iB1 = iB0 + 8, iB2 = iB0 + 16, iB3 = iB0 + 24;
                int sA0 = (iA0 < ea) ? csr_src[iA0] : -1;
                int sA1 = (iA1 < ea) ? csr_src[iA1] : -1;
                int sA2 = (iA2 < ea) ? csr_src[iA2] : -1;
                int sA3 = (iA3 < ea) ? csr_src[iA3] : -1;
                int sB0 = (iB0 < eb) ? csr_src[iB0] : -1;
                int sB1 = (iB1 < eb) ? csr_src[iB1] : -1;
                int sB2 = (iB2 < eb) ? csr_src[iB2] : -1;
                int sB3 = (iB3 < eb) ? csr_src[iB3] : -1;
                uint4 vA0 = {0,0,0,0}, vA1 = {0,0,0,0}, vA2 = {0,0,0,0}, vA3 = {0,0,0,0};
                uint4 vB0 = {0,0,0,0}, vB1 = {0,0,0,0}, vB2 = {0,0,0,0}, vB3 = {0,0,0,0};
                if (sA0 >= 0) vA0 = xr4[sA0 * 8 + q8];
                if (sA1 >= 0) vA1 = xr4[sA1 * 8 + q8];
                if (sA2 >= 0) vA2 = xr4[sA2 * 8 + q8];
                if (sA3 >= 0) vA3 = xr4[sA3 * 8 + q8];
                if (sB0 >= 0) vB0 = xr4[sB0 * 8 + q8];
                if (sB1 >= 0) vB1 = xr4[sB1 * 8 + q8];
                if (sB2 >= 0) vB2 = xr4[sB2 * 8 + q8];
                if (sB3 >= 0) vB3 = xr4[sB3 * 8 + q8];
                accA[0] += __uint_as_float(vA0.x << 16) + __uint_as_float(vA1.x << 16)
                         + __uint_as_float(vA2.x << 16) + __uint_as_float(vA3.x << 16);
                accA[1] += __uint_as_float(vA0.x & 0xffff0000u) + __uint_as_float(vA1.x & 0xffff0000u)
                         + __uint_as_float(vA2.x & 0xffff0000u) + __uint_as_float(vA3.x & 0xffff0000u);
                accA[2] += __uint_as_float(vA0.y << 16) + __uint_as_float(vA1.y << 16)
                         + __uint_as_float(vA2.y << 16) + __uint_as_float(vA3.y << 16);
                accA[3] += __uint_as_float(vA0.y & 0xffff0000u) + __uint_as_float(vA1.y & 0xffff0000u)
                         + __uint_as_float(vA2.y & 0xffff0000u) + __uint_as_float(vA3.y & 0xffff0000u);
                accA[4] += __uint_as_float(vA0.z << 16) + __uint_as_float(vA1.z << 16)
                         + __uint_as_float(vA2.z << 16) + __uint_as_float(vA3.z << 16);
                accA[5] += __uint_as_float(vA0.z & 0xffff0000u) + __uint_as_float(vA1.z & 0xffff0000u)
                         + __uint_as_float(vA2.z & 0xffff0000u) + __uint_as_float(vA3.z & 0xffff0000u);
                accA[6] += __uint_as_float(vA0.w << 16) + __uint_as_float(vA1.w << 16)
                         + __uint_as_float(vA2.w << 16) + __uint_as_float(vA3.w << 16);
                accA[7] += __uint_as_float(vA0.w & 0xffff0000u) + __uint_as_float(vA1.w & 0xffff0000u)
                         + __uint_as_float(vA2.w & 0xffff0000u) + __uint_as_float(vA3.w & 0xffff0000u);
                accB[0] += __uint_as_float(vB0.x << 16) + __uint_as_float(vB1.x << 16)
                         + __uint_as_float(vB2.x << 16) + __uint_as_float(vB3.x << 16);
                accB[1] += __uint_as_float(vB0.x & 0xffff0000u) + __uint_as_float(vB1.x & 0xffff0000u)
                         + __uint_as_float(vB2.x & 0xffff0000u) + __uint_as_float(vB3.x & 0xffff0000u);
                accB[2] += __uint_as_float(vB0.y << 16) + __uint_as_float(vB1.y << 16)
                         + __uint_as_float(vB2.y << 16) + __uint_as_float(vB3.y << 16);
                accB[3] += __uint_as_float(vB0.y & 0xffff0000u) + __uint_as_float(vB1.y & 0xffff0000u)
                         + __uint_as_float(vB2.y & 0xffff0000u) + __uint_as_float(vB3.y & 0xffff0000u);
                accB[4] += __uint_as_float(vB0.z << 16) + __uint_as_float(vB1.z << 16)
                         + __uint_as_float(vB2.z << 16) + __uint_as_float(vB3.z << 16);
                accB[5] += __uint_as_float(vB0.z & 0xffff0000u) + __uint_as_float(vB1.z & 0xffff0000u)
                         + __uint_as_float(vB2.z & 0xffff0000u) + __uint_as_float(vB3.z & 0xffff0000u);
                accB[6] += __uint_as_float(vB0.w << 16) + __uint_as_float(vB1.w << 16)
                         + __uint_as_float(vB2.w << 16) + __uint_as_float(vB3.w << 16);
                accB[7] += __uint_as_float(vB0.w & 0xffff0000u) + __uint_as_float(vB1.w & 0xffff0000u)
                         + __uint_as_float(vB2.w & 0xffff0000u) + __uint_as_float(vB3.w & 0xffff0000u);
            }
#pragma unroll
            for (int mm = 8; mm <= 32; mm <<= 1)
#pragma unroll
                for (int k = 0; k < 8; k++) {
                    accA[k] += __shfl_xor(accA[k], mm, 64);
                    accB[k] += __shfl_xor(accB[k], mm, 64);
                }
#pragma unroll
            for (int k = 0; k < 8; k++) {
                float vA = __shfl(accA[k], lane >> 3, 64);
                float vB = __shfl(accB[k], lane >> 3, 64);
                avA = ((lane & 7) == k) ? vA : avA;
                avB = ((lane & 7) == k) ? vB : avB;
            }
        } else {
            const uint4* xf = (const uint4*)x;  // fp32 row = 16 uint4
            for (int off = 0; off < maxd; off += 16) {
                int iA0 = sa + off + e4, iA1 = iA0 + 4, iA2 = iA0 + 8, iA3 = iA0 + 12;
                int iB0 = sb + off + e4, iB1 = iB0 + 4, iB2 = iB0 + 8, iB3 = iB0 + 12;
                int sA0 = (iA0 < ea) ? csr_src[iA0] : -1;
                int sA1 = (iA1 < ea) ? csr_src[iA1] : -1;
                int sA2 = (iA2 < ea) ? csr_src[iA2] : -1;
                int sA3 = (iA3 < ea) ? csr_src[iA3] : -1;
                int sB0 = (iB0 < eb) ? csr_src[iB0] : -1;
                int sB1 = (iB1 < eb) ? csr_src[iB1] : -1;
                int sB2 = (iB2 < eb) ? csr_src[iB2] : -1;
                int sB3 = (iB3 < eb) ? csr_src[iB3] : -1;
                uint4 vA0 = {0,0,0,0}, vA1 = {0,0,0,0}, vA2 = {0,0,0,0}, vA3 = {0,0,0,0};
                uint4 vB0 = {0,0,0,0}, vB1 = {0,0,0,0}, vB2 = {0,0,0,0}, vB3 = {0,0,0,0};
                if (sA0 >= 0) vA0 = xf[sA0 * 16 + q16];
                if (sA1 >= 0) vA1 = xf[sA1 * 16 + q16];
                if (sA2 >= 0) vA2 = xf[sA2 * 16 + q16];
                if (sA3 >= 0) vA3 = xf[sA3 * 16 + q16];
                if (sB0 >= 0) vB0 = xf[sB0 * 16 + q16];
                if (sB1 >= 0) vB1 = xf[sB1 * 16 + q16];
                if (sB2 >= 0) vB2 = xf[sB2 * 16 + q16];
                if (sB3 >= 0) vB3 = xf[sB3 * 16 + q16];
                accA[0] += __uint_as_float(vA0.x) + __uint_as_float(vA1.x)
                         + __uint_as_float(vA2.x) + __uint_as_float(vA3.x);
                accA[1] += __uint_as_float(vA0.y) + __uint_as_float(vA1.y)
                         + __uint_as_float(vA2.y) + __uint_as_float(vA3.y);
                accA[2] += __uint_as_float(vA0.z) + __uint_as_float(vA1.z)
                         + __uint_as_float(vA2.z) + __uint_as_float(vA3.z);
                accA[3] += __uint_as_float(vA0.w) + __uint_as_float(vA1.w)
                         + __uint_as_float(vA2.w) + __uint_as_float(vA3.w);
                accB[0] += __uint_as_float(vB0.x) + __uint_as_float(vB1.x)
                         + __uint_as_float(vB2.x) + __uint_as_float(vB3.x);
                accB[1] += __uint_as_float(vB0.y) + __uint_as_float(vB1.y)
                         + __uint_as_float(vB2.y) + __uint_as_float(vB3.y);
                accB[2] += __uint_as_float(vB0.z) + __uint_as_float(vB1.z)
                         + __uint_as_float(vB2.z) + __uint_as_float(vB3.z);
                accB[3] += __uint_as_float(vB0.w) + __uint_as_float(vB1.w)
                         + __uint_as_float(vB2.w) + __uint_as_float(vB3.w);
            }
#pragma unroll
            for (int mm = 16; mm <= 32; mm <<= 1)
#pragma unroll
                for (int k = 0; k < 4; k++) {
                    accA[k] += __shfl_xor(accA[k], mm, 64);
                    accB[k] += __shfl_xor(accB[k], mm, 64);
                }
#pragma unroll
            for (int k = 0; k < 4; k++) {
                float vA = __shfl(accA[k], lane >> 2, 64);
                float vB = __shfl(accB[k], lane >> 2, 64);
                avA = ((lane & 3) == k) ? vA : avA;
                avB = ((lane & 3) == k) ? vB : avB;
            }
        }
        avA *= 1.0f / fmaxf((float)da, 1.0f);
        avB *= 1.0f / fmaxf((float)db, 1.0f);
        aggbuf[(long long)na * 64 + lane] = __float2bfloat16(avA);
        aggbuf[(long long)nb * 64 + lane] = __float2bfloat16(avB);
    }
}

// ---------------- layer-1+2 GEMMs (MFMA, dense coalesced staging) ----------------
__global__ __launch_bounds__(256) void gemm1_kernel(
    const void* __restrict__ x, const bf16* __restrict__ aggbuf,
    const void* __restrict__ W1l, const void* __restrict__ b1l,
    const void* __restrict__ W1r, const void* __restrict__ W2l,
    const void* __restrict__ b2l, const void* __restrict__ W2r,
    bf16* __restrict__ zbuf, bf16* __restrict__ rbuf,
    const int* __restrict__ flags) {
    __shared__ __align__(16) unsigned short sW1t[64][136];
    __shared__ __align__(16) unsigned short sA[64][136];
    __shared__ __align__(16) unsigned short sW2t[64][72];
    __shared__ __align__(16) unsigned short sH[64][72];
    __shared__ float sB1[64];
    __shared__ float sB2[32];

    int isbf = flags[0];
    int t = threadIdx.x;
    int n0 = blockIdx.x * 64;

    for (int i = t; i < 64 * 128; i += 256) {
        int n = i & 63, k = i >> 6;
        unsigned short v;
        if (isbf)
            v = (k < 64) ? ((const unsigned short*)W1l)[k * 64 + n]
                         : ((const unsigned short*)W1r)[(k - 64) * 64 + n];
        else
            v = f2bits((k < 64) ? ((const float*)W1l)[k * 64 + n]
                                : ((const float*)W1r)[(k - 64) * 64 + n]);
        sW1t[n][k] = v;
    }
    for (int i = t; i < 64 * 64; i += 256) {
        int n = i & 63, k = i >> 6;
        unsigned short v;
        if (isbf)
            v = (n < 32) ? ((const unsigned short*)W2l)[k * 32 + n]
                         : ((const unsigned short*)W2r)[k * 32 + (n - 32)];
        else
            v = f2bits((n < 32) ? ((const float*)W2l)[k * 32 + n]
                                : ((const float*)W2r)[k * 32 + (n - 32)]);
        sW2t[n][k] = v;
    }
    if (t < 64) sB1[t] = get_f(b1l, t, isbf);
    if (t < 32) sB2[t] = get_f(b2l, t, isbf);

    const uint4* ag4 = (const uint4*)aggbuf;
    if (isbf) {
        const uint4* x4 = (const uint4*)x;
        for (int i = t; i < 64 * 16; i += 256) {
            int m = i >> 4, c = i & 15;
            int nn = min(n0 + m, N_NODES - 1);
            uint4 v = (c < 8) ? ag4[(long long)nn * 8 + c]
                              : x4[(long long)nn * 8 + (c - 8)];
            *(uint4*)&sA[m][c * 8] = v;
        }
    } else {
        for (int i = t; i < 64 * 8; i += 256) {
            int m = i >> 3, c = i & 7;
            int nn = min(n0 + m, N_NODES - 1);
            *(uint4*)&sA[m][c * 8] = ag4[(long long)nn * 8 + c];
        }
        const float* xf = (const float*)x;
        for (int i = t; i < 64 * 64; i += 256) {
            int m = i >> 6, c = i & 63;
            int nn = min(n0 + m, N_NODES - 1);
            sA[m][64 + c] = f2bf_bits(xf[(long long)nn * 64 + c]);
        }
    }
    __syncthreads();

    int w = t >> 6, lane = t & 63;
    int mbase = w * 16;
    int q = lane >> 4, r15 = lane & 15;
    f32x4 acc1[4] = {{0,0,0,0},{0,0,0,0},{0,0,0,0},{0,0,0,0}};
#pragma unroll
    for (int ks = 0; ks < 4; ks++) {
        bf16x8 afrag = *(const bf16x8*)&sA[mbase + r15][ks * 32 + q * 8];
#pragma unroll
        for (int nt = 0; nt < 4; nt++) {
            bf16x8 bfrag = *(const bf16x8*)&sW1t[nt * 16 + r15][ks * 32 + q * 8];
            acc1[nt] = __builtin_amdgcn_mfma_f32_16x16x32_bf16(afrag, bfrag, acc1[nt], 0, 0, 0);
        }
    }
#pragma unroll
    for (int nt = 0; nt < 4; nt++) {
        int col = nt * 16 + r15;
        float bias = sB1[col];
#pragma unroll
        for (int rr = 0; rr < 4; rr++) {
            int m = mbase + q * 4 + rr;
            sH[m][col] = f2bf_bits(fmaxf(acc1[nt][rr] + bias, 0.0f));
        }
    }
    __syncthreads();

    f32x4 acc2[4] = {{0,0,0,0},{0,0,0,0},{0,0,0,0},{0,0,0,0}};
#pragma unroll
    for (int ks = 0; ks < 2; ks++) {
        bf16x8 afrag = *(const bf16x8*)&sH[mbase + r15][ks * 32 + q * 8];
#pragma unroll
        for (int nt = 0; nt < 4; nt++) {
            bf16x8 bfrag = *(const bf16x8*)&sW2t[nt * 16 + r15][ks * 32 + q * 8];
            acc2[nt] = __builtin_amdgcn_mfma_f32_16x16x32_bf16(afrag, bfrag, acc2[nt], 0, 0, 0);
        }
    }
#pragma unroll
    for (int nt = 0; nt < 4; nt++) {
        int col = nt * 16 + r15;
#pragma unroll
        for (int rr = 0; rr < 4; rr++) {
            int m = mbase + q * 4 + rr;
            int n = n0 + m;
            if (n < N_NODES) {
                float v = acc2[nt][rr];
                if (col < 32)
                    zbuf[(long long)n * 32 + col] = __float2bfloat16(v);
                else
                    rbuf[(long long)n * 32 + (col - 32)] = __float2bfloat16(v + sB2[col - 32]);
            }
        }
    }
}

// ---------------- layer-2: gather z, 2 nodes/wave, 4 loads in flight ----------------
__global__ void node2_kernel(const int* __restrict__ row_start,
                             const int* __restrict__ csr_src,
                             const bf16* __restrict__ z,
                             const bf16* __restrict__ rbuf,
                             void* __restrict__ out,
                             const int* __restrict__ flags) {
    int isbf = flags[0];
    int t = threadIdx.x;
    int lane = t & 63;
    int e = lane >> 2, q = lane & 3;  // 16 edges x 4 chunks per load
    int gw = (blockIdx.x * blockDim.x + t) >> 6;
    int nwaves = (gridDim.x * blockDim.x) >> 6;
    const uint4* zr = (const uint4*)z;

    for (int p = gw; p * 2 < N_NODES; p += nwaves) {
        int na = p * 2, nb = p * 2 + 1;
        int sa = row_start[na], ea = row_start[na + 1];
        int sb = row_start[nb], eb = row_start[nb + 1];
        float accA[8] = {0, 0, 0, 0, 0, 0, 0, 0};
        float accB[8] = {0, 0, 0, 0, 0, 0, 0, 0};
        int da = ea - sa, db = eb - sb;
        int maxd = max(da, db);
        for (int off = 0; off < maxd; off += 32) {
            int iA0 = sa + off + e, iA1 = iA0 + 16;
            int iB0 = sb + off + e, iB1 = iB0 + 16;
            int sA0 = (iA0 < ea) ? csr_src[iA0] : -1;
            int sA1 = (iA1 < ea) ? csr_src[iA1] : -1;
            int sB0 = (iB0 < eb) ? csr_src[iB0] : -1;
            int sB1 = (iB1 < eb) ? csr_src[iB1] : -1;
            uint4 vA0 = {0,0,0,0}, vA1 = {0,0,0,0}, vB0 = {0,0,0,0}, vB1 = {0,0,0,0};
            if (sA0 >= 0) vA0 = zr[sA0 * 4 + q];
            if (sA1 >= 0) vA1 = zr[sA1 * 4 + q];
            if (sB0 >= 0) vB0 = zr[sB0 * 4 + q];
            if (sB1 >= 0) vB1 = zr[sB1 * 4 + q];
            accA[0] += __uint_as_float(vA0.x << 16) + __uint_as_float(vA1.x << 16);
            accA[1] += __uint_as_float(vA0.x & 0xffff0000u) + __uint_as_float(vA1.x & 0xffff0000u);
            accA[2] += __uint_as_float(vA0.y << 16) + __uint_as_float(vA1.y << 16);
            accA[3] += __uint_as_float(vA0.y & 0xffff0000u) + __uint_as_float(vA1.y & 0xffff0000u);
            accA[4] += __uint_as_float(vA0.z << 16) + __uint_as_float(vA1.z << 16);
            accA[5] += __uint_as_float(vA0.z & 0xffff0000u) + __uint_as_float(vA1.z & 0xffff0000u);
            accA[6] += __uint_as_float(vA0.w << 16) + __uint_as_float(vA1.w << 16);
            accA[7] += __uint_as_float(vA0.w & 0xffff0000u) + __uint_as_float(vA1.w & 0xffff0000u);
            accB[0] += __uint_as_float(vB0.x << 16) + __uint_as_float(vB1.x << 16);
            accB[1] += __uint_as_float(vB0.x & 0xffff0000u) + __uint_as_float(vB1.x & 0xffff0000u);
            accB[2] += __uint_as_float(vB0.y << 16) + __uint_as_float(vB1.y << 16);
            accB[3] += __uint_as_float(vB0.y & 0xffff0000u) + __uint_as_float(vB1.y & 0xffff0000u);
            accB[4] += __uint_as_float(vB0.z << 16) + __uint_as_float(vB1.z << 16);
            accB[5] += __uint_as_float(vB0.z & 0xffff0000u) + __uint_as_float(vB1.z & 0xffff0000u);
            accB[6] += __uint_as_float(vB0.w << 16) + __uint_as_float(vB1.w << 16);
            accB[7] += __uint_as_float(vB0.w & 0xffff0000u) + __uint_as_float(vB1.w & 0xffff0000u);
        }
#pragma unroll
        for (int m = 4; m <= 32; m <<= 1)
#pragma unroll
            for (int k = 0; k < 8; k++) {
                accA[k] += __shfl_xor(accA[k], m, 64);
                accB[k] += __shfl_xor(accB[k], m, 64);
            }
        float svA = 0.0f, svB = 0.0f;
#pragma unroll
        for (int k = 0; k < 8; k++) {
            float vA = __shfl(accA[k], lane >> 3, 64);
            float vB = __shfl(accB[k], lane >> 3, 64);
            svA = ((lane & 7) == k) ? vA : svA;
            svB = ((lane & 7) == k) ? vB : svB;
        }
        if (lane < 32) {
            float invA = 1.0f / fmaxf((float)da, 1.0f);
            float invB = 1.0f / fmaxf((float)db, 1.0f);
            float valA = svA * invA + b2f(rbuf[(long long)na * 32 + lane]);
            float valB = svB * invB + b2f(rbuf[(long long)nb * 32 + lane]);
            if (isbf) {
                ((bf16*)out)[(long long)na * 32 + lane] = __float2bfloat16(valA);
                ((bf16*)out)[(long long)nb * 32 + lane] = __float2bfloat16(valB);
            } else {
                ((float*)out)[(long long)na * 32 + lane] = valA;
                ((float*)out)[(long long)nb * 32 + lane] = valB;
            }
        }
    }
}

extern "C" void kernel_launch(void* const* d_in, const int* in_sizes, int n_in,
                              void* d_out, int out_size, void* d_ws, size_t ws_size,
                              hipStream_t stream) {
    const void* x = d_in[0];
    const void* ei = d_in[1];  // [2, E]: src = [0,E), dst = [E,2E)
    const void* W1l = d_in[2];
    const void* b1l = d_in[3];
    const void* W1r = d_in[4];
    const void* W2l = d_in[5];
    const void* b2l = d_in[6];
    const void* W2r = d_in[7];

    // workspace layout (~42 MB). aggbuf ALIASES bucket_data (dead after csrB).
    char* ws = (char*)d_ws;
    uint* bucket_data = (uint*)ws;                    // NBKT*BKT_CAP u32 = 16.0 MB
    bf16* aggbuf = (bf16*)ws;                         // N*64 bf16 = 12.8 MB (alias)
    int* csr_src = (int*)(ws + 16015424);             // E i32 = 12.8 MB
    int* row_start = (int*)(ws + 28815424);           // N+1 i32
    int* bucket_cursor = (int*)(ws + 29215488);       // NBKT i32
    int* bucket_base = (int*)(ws + 29217088);         // NBKT i32
    bf16* zbuf = (bf16*)(ws + 29218688);              // N*32 bf16 = 6.4 MB
    bf16* rbuf = (bf16*)(ws + 35618688);              // N*32 bf16 = 6.4 MB
    int* flags = (int*)(ws + 42018688);               // 2 i32

    hipMemsetAsync(bucket_cursor, 0, NBKT * 4, stream);

    detect_kernel<<<1, 64, 0, stream>>>(x, ei, flags);
    scatterA_kernel<<<NBKT, 256, 0, stream>>>(ei, bucket_cursor, bucket_data, flags);
    scanBuckets_kernel<<<1, 512, 0, stream>>>(bucket_cursor, bucket_base);
    csrB_kernel<<<NBKT, 256, 0, stream>>>(bucket_cursor, bucket_base, bucket_data,
                                          csr_src, row_start);
    gather1_kernel<<<3125, 256, 0, stream>>>(x, row_start, csr_src, aggbuf, flags);
    gemm1_kernel<<<1563, 256, 0, stream>>>(x, aggbuf, W1l, b1l, W1r, W2l, b2l,
                                           W2r, zbuf, rbuf, flags);
    node2_kernel<<<8192, 256, 0, stream>>>(row_start, csr_src, zbuf, rbuf, d_out,
                                           flags);
}